// Round 8
// baseline (75.307 us; speedup 1.0000x reference)
//
#include <hip/hip_runtime.h>

#define NPTS 8192
#define THREADS 256
#define G 4096                      // buckets per plane
#define LO (-6.0f)
#define BW (12.0f / (float)G)       // bucket width
#define INVW ((float)G / 12.0f)
#define NQ (6 * NPTS)               // 49152 total queries
#define QBLKS (NQ / THREADS)        // 192

// ws layout: sorted[6][8192] f32 | start[6][4097] i32 | partials[192] f32 | counter u32
#define WS_SORTED 0
#define WS_START  (6 * NPTS)
#define WS_PART   (WS_START + 6 * (G + 1))
#define WS_CNT    (WS_PART + QBLKS)

__device__ __forceinline__ int bucket_of(float v) {
    int b = (int)((v - LO) * INVW);
    return min(max(b, 0), G - 1);
}

// K1: one block per plane (arr in {pred,target} x ch in {x,y,z}).
// Counting-sort the plane's 8192 values into CSR (sorted + start) via LDS
// histogram -> exclusive scan -> scatter. Also zeroes the finisher counter.
__global__ __launch_bounds__(THREADS) void build_kernel(
    const float* __restrict__ pred, const float* __restrict__ target,
    float* __restrict__ sorted, int* __restrict__ start,
    unsigned int* __restrict__ counter)
{
    const int p   = blockIdx.x;       // 0..5
    const int arr = p / 3, ch = p - arr * 3;
    const float* src = arr ? target : pred;

    __shared__ float    vals[NPTS];       // 32 KB
    __shared__ unsigned hist[G];          // 16 KB (becomes starts)
    __shared__ unsigned curs[G];          // 16 KB scatter cursors
    __shared__ unsigned wtot[4];

    const int t = threadIdx.x, lane = t & 63, wave = t >> 6;

    for (int i = t; i < G; i += THREADS) hist[i] = 0u;
    for (int i = t; i < NPTS; i += THREADS) vals[i] = src[i * 3 + ch];
    __syncthreads();

    for (int i = t; i < NPTS; i += THREADS)
        atomicAdd(&hist[bucket_of(vals[i])], 1u);
    __syncthreads();

    // exclusive scan of hist[G] across the block (16 bins per thread)
    const int BPT = G / THREADS;      // 16
    unsigned cnt[BPT], tsum = 0;
    #pragma unroll
    for (int j = 0; j < BPT; ++j) { cnt[j] = hist[t * BPT + j]; tsum += cnt[j]; }

    unsigned inc = tsum;
    #pragma unroll
    for (int off = 1; off < 64; off <<= 1) {
        unsigned n = __shfl_up(inc, off, 64);
        if (lane >= off) inc += n;
    }
    if (lane == 63) wtot[wave] = inc;
    __syncthreads();
    unsigned woff = 0;
    for (int w = 0; w < wave; ++w) woff += wtot[w];
    unsigned run = woff + (inc - tsum);

    #pragma unroll
    for (int j = 0; j < BPT; ++j) {
        hist[t * BPT + j] = run;          // exclusive start (own bins only)
        curs[t * BPT + j] = run;
        start[p * (G + 1) + t * BPT + j] = (int)run;
        run += cnt[j];
    }
    if (t == 0) {
        start[p * (G + 1) + G] = NPTS;
        if (p == 0) *counter = 0u;        // fresh finisher counter every call
    }
    __syncthreads();

    // scatter (intra-bucket order nondeterministic; consumers only take min)
    for (int i = t; i < NPTS; i += THREADS) {
        const float v = vals[i];
        const unsigned pos = atomicAdd(&curs[bucket_of(v)], 1u);
        sorted[p * NPTS + pos] = v;
    }
}

// K2: one thread per query (from the ORIGINAL arrays -> fixed order,
// bitwise-deterministic sums). Ring-scan buckets outward; elements in ring d
// are at distance >= (d-1)*BW, so stop when (d-1)*BW >= current min.
// Block partial sums -> last-done block reduces 192 partials -> out.
__global__ __launch_bounds__(THREADS) void query_kernel(
    const float* __restrict__ pred, const float* __restrict__ target,
    const float* __restrict__ sorted, const int* __restrict__ start,
    float* __restrict__ partials, unsigned int* __restrict__ counter,
    float* __restrict__ out)
{
    const int t = threadIdx.x;
    const int i = blockIdx.x * THREADS + t;      // 0..49151
    const int qarr = i / (3 * NPTS);
    const int r    = i - qarr * (3 * NPTS);
    const int qch  = r >> 13;                    // /8192
    const int qi   = r & (NPTS - 1);

    const float x = (qarr ? target : pred)[qi * 3 + qch];
    const int cp  = (1 - qarr) * 3 + qch;        // candidate plane
    const int*   st = start + cp * (G + 1);
    const float* cs = sorted + cp * NPTS;

    const int bx = bucket_of(x);
    float m = 3.0e38f;
    for (int d = 0; d < G; ++d) {
        if (d > 0 && (float)(d - 1) * BW >= m) break;
        const int bl = bx - d, br = bx + d;
        if (bl >= 0) {
            const int e = st[bl + 1];
            for (int k = st[bl]; k < e; ++k) m = fminf(m, fabsf(x - cs[k]));
        }
        if (d > 0 && br < G) {
            const int e = st[br + 1];
            for (int k = st[br]; k < e; ++k) m = fminf(m, fabsf(x - cs[k]));
        }
    }

    // block sum
    float sum = m;
    #pragma unroll
    for (int off = 32; off > 0; off >>= 1)
        sum += __shfl_down(sum, off, 64);
    __shared__ float wsum[4];
    __shared__ int isfin;
    if ((t & 63) == 0) wsum[t >> 6] = sum;
    __syncthreads();

    if (t == 0) {
        const float psum = (wsum[0] + wsum[1]) + (wsum[2] + wsum[3]);
        atomicExch(&partials[blockIdx.x], psum);
        __threadfence();
        isfin = (atomicAdd(counter, 1u) == QBLKS - 1);
    }
    __syncthreads();

    if (isfin) {
        __threadfence();
        float s = (t < QBLKS) ? atomicAdd(&partials[t], 0.0f) : 0.f;
        #pragma unroll
        for (int off = 32; off > 0; off >>= 1)
            s += __shfl_down(s, off, 64);
        if ((t & 63) == 0) wsum[t >> 6] = s;
        __syncthreads();
        if (t == 0)
            out[0] = ((wsum[0] + wsum[1]) + (wsum[2] + wsum[3])) * (1.0f / NPTS);
    }
}

extern "C" void kernel_launch(void* const* d_in, const int* in_sizes, int n_in,
                              void* d_out, int out_size, void* d_ws, size_t ws_size,
                              hipStream_t stream) {
    const float* pred   = (const float*)d_in[0];
    const float* target = (const float*)d_in[1];
    float* out = (float*)d_out;
    float* wsf = (float*)d_ws;

    float*        sorted   = wsf + WS_SORTED;
    int*          start    = (int*)(wsf + WS_START);
    float*        partials = wsf + WS_PART;
    unsigned int* counter  = (unsigned int*)(wsf + WS_CNT);

    build_kernel<<<6, THREADS, 0, stream>>>(pred, target, sorted, start, counter);
    query_kernel<<<QBLKS, THREADS, 0, stream>>>(pred, target, sorted, start,
                                                partials, counter, out);
}

// Round 9
// 21.319 us; speedup vs baseline: 3.5323x; 3.5323x over previous
//
#include <hip/hip_runtime.h>

#define NPTS 8192
#define G 4096                      // buckets per plane
#define LOF (-6.0f)
#define BWF (12.0f / (float)G)      // bucket width
#define INVW ((float)G / 12.0f)
#define NQ (6 * NPTS)               // 49152 queries
#define QTHREADS 256
#define QBLKS (NQ / QTHREADS)       // 192
#define BTHREADS 1024
#define VPT (NPTS / BTHREADS)       // 8 values per build thread
#define KWIN 16                     // initial one-sided window (positions)
#define KEXP 32                     // expansion step (positions, mult of 4)

// ws float layout: sorted[6][NPTS] | start[6][G+1] | partials[QBLKS] | counter
#define WS_SORTED 0
#define WS_START  (6 * NPTS)
#define WS_PART   (WS_START + 6 * (G + 1))
#define WS_CNT    (WS_PART + QBLKS)

__device__ __forceinline__ int bucket_of(float v) {
    int b = (int)((v - LOF) * INVW);
    return min(max(b, 0), G - 1);
}

// K1: one block per plane, 1024 threads. Values in registers; LDS histogram
// -> shfl exclusive scan -> CSR start[] -> scatter. Zeroes finisher counter.
__global__ __launch_bounds__(BTHREADS) void build_kernel(
    const float* __restrict__ pred, const float* __restrict__ target,
    float* __restrict__ sorted, int* __restrict__ start,
    unsigned int* __restrict__ counter)
{
    const int p   = blockIdx.x;       // 0..5
    const int arr = p / 3, ch = p - arr * 3;
    const float* src = arr ? target : pred;

    __shared__ unsigned hist[G];      // 16 KB
    __shared__ unsigned curs[G];      // 16 KB
    __shared__ unsigned wtot[BTHREADS / 64];

    const int t = threadIdx.x, lane = t & 63, wave = t >> 6;

    float v[VPT];
    #pragma unroll
    for (int j = 0; j < VPT; ++j)
        v[j] = src[(t + j * BTHREADS) * 3 + ch];

    #pragma unroll
    for (int i = t; i < G; i += BTHREADS) hist[i] = 0u;
    __syncthreads();

    #pragma unroll
    for (int j = 0; j < VPT; ++j)
        atomicAdd(&hist[bucket_of(v[j])], 1u);
    __syncthreads();

    // exclusive scan over G bins; BPT = 4 bins/thread
    const int BPT = G / BTHREADS;     // 4
    unsigned cnt[BPT], tsum = 0;
    #pragma unroll
    for (int j = 0; j < BPT; ++j) { cnt[j] = hist[t * BPT + j]; tsum += cnt[j]; }

    unsigned inc = tsum;
    #pragma unroll
    for (int off = 1; off < 64; off <<= 1) {
        unsigned n = __shfl_up(inc, off, 64);
        if (lane >= off) inc += n;
    }
    if (lane == 63) wtot[wave] = inc;
    __syncthreads();
    unsigned woff = 0;
    for (int w = 0; w < wave; ++w) woff += wtot[w];
    unsigned run = woff + (inc - tsum);

    #pragma unroll
    for (int j = 0; j < BPT; ++j) {
        curs[t * BPT + j] = run;
        start[p * (G + 1) + t * BPT + j] = (int)run;
        run += cnt[j];
    }
    if (t == 0) {
        start[p * (G + 1) + G] = NPTS;
        if (p == 0) *counter = 0u;    // fresh each call: replay/poison-safe
    }
    __syncthreads();

    #pragma unroll
    for (int j = 0; j < VPT; ++j) {
        const unsigned pos = atomicAdd(&curs[bucket_of(v[j])], 1u);
        sorted[p * NPTS + pos] = v[j]; // intra-bucket order irrelevant (min)
    }
}

// K2: one thread per query. Contiguous position-window scan around the
// query's bucket start: all loads independent (float4), ~2 latency stages.
// Exact: stop only when bucket-edge bounds prove no unscanned element wins.
__global__ __launch_bounds__(QTHREADS) void query_kernel(
    const float* __restrict__ pred, const float* __restrict__ target,
    const float* __restrict__ sorted, const int* __restrict__ start,
    float* __restrict__ partials, unsigned int* __restrict__ counter,
    float* __restrict__ out)
{
    const int t = threadIdx.x;
    const int i = blockIdx.x * QTHREADS + t;
    const int qarr = i / (3 * NPTS);
    const int r    = i - qarr * (3 * NPTS);
    const int qch  = r >> 13;
    const int qi   = r & (NPTS - 1);

    const float x = (qarr ? target : pred)[qi * 3 + qch];  // fixed order
    const int cp  = (1 - qarr) * 3 + qch;
    const int*   st = start + cp * (G + 1);
    const float* cs = sorted + cp * NPTS;

    const int bx = bucket_of(x);
    const int p0 = st[bx], p1 = st[bx + 1];

    int lo = max(p0 - KWIN, 0) & ~3;
    int hi = min(p1 + KWIN, NPTS);
    hi = (hi + 3) & ~3;               // NPTS % 4 == 0 -> stays <= NPTS

    float m0 = 3.0e38f, m1 = 3.0e38f;
    const float4* c4 = (const float4*)cs;
    for (int k = lo >> 2; k < (hi >> 2); ++k) {
        const float4 c = c4[k];       // independent loads: pipelined
        m0 = fminf(m0, fminf(fabsf(x - c.x), fabsf(x - c.y)));
        m1 = fminf(m1, fminf(fabsf(x - c.z), fabsf(x - c.w)));
    }
    float m = fminf(m0, m1);

    // bounds: unscanned lower elems < upper edge of bucket(cs[lo]);
    //         unscanned higher elems >= lower edge of bucket(cs[hi-1]).
    float bl = (lo == 0)    ? 3.0e38f
             : x - (LOF + (float)(bucket_of(cs[lo]) + 1) * BWF);
    float br = (hi >= NPTS) ? 3.0e38f
             : (LOF + (float)bucket_of(cs[hi - 1]) * BWF) - x;

    while (m > fminf(bl, br)) {       // rare (tails / edge-straddling x)
        if (bl <= br) {
            const int nlo = max(lo - KEXP, 0);
            for (int k = nlo >> 2; k < (lo >> 2); ++k) {
                const float4 c = c4[k];
                m = fminf(m, fminf(fminf(fabsf(x - c.x), fabsf(x - c.y)),
                                   fminf(fabsf(x - c.z), fabsf(x - c.w))));
            }
            lo = nlo;
            bl = (lo == 0) ? 3.0e38f
               : x - (LOF + (float)(bucket_of(cs[lo]) + 1) * BWF);
        } else {
            const int nhi = min(hi + KEXP, NPTS);
            for (int k = hi >> 2; k < (nhi >> 2); ++k) {
                const float4 c = c4[k];
                m = fminf(m, fminf(fminf(fabsf(x - c.x), fabsf(x - c.y)),
                                   fminf(fabsf(x - c.z), fabsf(x - c.w))));
            }
            hi = nhi;
            br = (hi >= NPTS) ? 3.0e38f
               : (LOF + (float)bucket_of(cs[hi - 1]) * BWF) - x;
        }
    }

    // block sum -> counter-finisher (proven in R6-R8)
    float sum = m;
    #pragma unroll
    for (int off = 32; off > 0; off >>= 1)
        sum += __shfl_down(sum, off, 64);
    __shared__ float wsum[4];
    __shared__ int isfin;
    if ((t & 63) == 0) wsum[t >> 6] = sum;
    __syncthreads();

    if (t == 0) {
        const float psum = (wsum[0] + wsum[1]) + (wsum[2] + wsum[3]);
        atomicExch(&partials[blockIdx.x], psum);
        __threadfence();
        isfin = (atomicAdd(counter, 1u) == QBLKS - 1);
    }
    __syncthreads();

    if (isfin) {
        __threadfence();
        float s = (t < QBLKS) ? atomicAdd(&partials[t], 0.0f) : 0.f;
        #pragma unroll
        for (int off = 32; off > 0; off >>= 1)
            s += __shfl_down(s, off, 64);
        if ((t & 63) == 0) wsum[t >> 6] = s;
        __syncthreads();
        if (t == 0)
            out[0] = ((wsum[0] + wsum[1]) + (wsum[2] + wsum[3])) * (1.0f / NPTS);
    }
}

extern "C" void kernel_launch(void* const* d_in, const int* in_sizes, int n_in,
                              void* d_out, int out_size, void* d_ws, size_t ws_size,
                              hipStream_t stream) {
    const float* pred   = (const float*)d_in[0];
    const float* target = (const float*)d_in[1];
    float* out = (float*)d_out;
    float* wsf = (float*)d_ws;

    float*        sorted   = wsf + WS_SORTED;
    int*          start    = (int*)(wsf + WS_START);
    float*        partials = wsf + WS_PART;
    unsigned int* counter  = (unsigned int*)(wsf + WS_CNT);

    build_kernel<<<6, BTHREADS, 0, stream>>>(pred, target, sorted, start, counter);
    query_kernel<<<QBLKS, QTHREADS, 0, stream>>>(pred, target, sorted, start,
                                                 partials, counter, out);
}

// Round 10
// 19.676 us; speedup vs baseline: 3.8273x; 1.0835x over previous
//
#include <hip/hip_runtime.h>

#define NPTS 8192
#define G 4096                      // buckets per plane
#define LOF (-6.0f)
#define BWF (12.0f / (float)G)      // bucket width
#define INVW ((float)G / 12.0f)
#define NQ (6 * NPTS)               // 49152 queries
#define QTHREADS 128
#define QBLKS (NQ / QTHREADS)       // 384
#define BTHREADS 1024
#define VPT (NPTS / BTHREADS)       // 8 values per build thread
#define KWIN 16                     // initial one-sided window (positions)
#define KEXP 32                     // expansion step (positions, mult of 4)

// ws float layout: sorted[6][NPTS] | start[6][G+1] | qv[6][NPTS] | partials[QBLKS]
#define WS_SORTED 0
#define WS_START  (6 * NPTS)
#define WS_QV     (WS_START + 6 * (G + 1))
#define WS_PART   (WS_QV + 6 * NPTS)

__device__ __forceinline__ int bucket_of(float v) {
    int b = (int)((v - LOF) * INVW);
    return min(max(b, 0), G - 1);
}

// K1: one block per plane, 1024 threads. Values in registers; LDS histogram
// -> shfl exclusive scan -> CSR start[] -> scatter. Also writes the
// deinterleaved query copy qv (coalesced) so K2's x-load is coalesced.
__global__ __launch_bounds__(BTHREADS) void build_kernel(
    const float* __restrict__ pred, const float* __restrict__ target,
    float* __restrict__ sorted, int* __restrict__ start,
    float* __restrict__ qv)
{
    const int p   = blockIdx.x;       // 0..5
    const int arr = p / 3, ch = p - arr * 3;
    const float* src = arr ? target : pred;

    __shared__ unsigned hist[G];      // 16 KB
    __shared__ unsigned curs[G];      // 16 KB
    __shared__ unsigned wtot[BTHREADS / 64];

    const int t = threadIdx.x, lane = t & 63, wave = t >> 6;

    float v[VPT];
    #pragma unroll
    for (int j = 0; j < VPT; ++j)
        v[j] = src[(t + j * BTHREADS) * 3 + ch];

    #pragma unroll
    for (int i = t; i < G; i += BTHREADS) hist[i] = 0u;
    __syncthreads();

    #pragma unroll
    for (int j = 0; j < VPT; ++j) {
        qv[p * NPTS + t + j * BTHREADS] = v[j];       // coalesced
        atomicAdd(&hist[bucket_of(v[j])], 1u);
    }
    __syncthreads();

    // exclusive scan over G bins; BPT = 4 bins/thread
    const int BPT = G / BTHREADS;     // 4
    unsigned cnt[BPT], tsum = 0;
    #pragma unroll
    for (int j = 0; j < BPT; ++j) { cnt[j] = hist[t * BPT + j]; tsum += cnt[j]; }

    unsigned inc = tsum;
    #pragma unroll
    for (int off = 1; off < 64; off <<= 1) {
        unsigned n = __shfl_up(inc, off, 64);
        if (lane >= off) inc += n;
    }
    if (lane == 63) wtot[wave] = inc;
    __syncthreads();
    unsigned woff = 0;
    for (int w = 0; w < wave; ++w) woff += wtot[w];
    unsigned run = woff + (inc - tsum);

    #pragma unroll
    for (int j = 0; j < BPT; ++j) {
        curs[t * BPT + j] = run;
        start[p * (G + 1) + t * BPT + j] = (int)run;
        run += cnt[j];
    }
    if (t == 0) start[p * (G + 1) + G] = NPTS;
    __syncthreads();

    #pragma unroll
    for (int j = 0; j < VPT; ++j) {
        const unsigned pos = atomicAdd(&curs[bucket_of(v[j])], 1u);
        sorted[p * NPTS + pos] = v[j]; // intra-bucket order irrelevant (exact min)
    }
}

// K2: one thread per query (x from qv: coalesced). Contiguous position-window
// scan around the query's bucket; independent float4 loads; bucket-edge
// bounds prove exactness. Plain-store block partials - NO global atomics.
__global__ __launch_bounds__(QTHREADS) void query_kernel(
    const float* __restrict__ qv,
    const float* __restrict__ sorted, const int* __restrict__ start,
    float* __restrict__ partials)
{
    const int t = threadIdx.x;
    const int i = blockIdx.x * QTHREADS + t;
    const int q  = i >> 13;                      // own plane 0..5
    const int cp = (q + 3) % 6;                  // candidate plane (other array)

    const float x = qv[i];
    const int*   st = start + cp * (G + 1);
    const float* cs = sorted + cp * NPTS;

    const int bx = bucket_of(x);
    const int p0 = st[bx], p1 = st[bx + 1];

    int lo = max(p0 - KWIN, 0) & ~3;
    int hi = min(p1 + KWIN, NPTS);
    hi = (hi + 3) & ~3;

    float m0 = 3.0e38f, m1 = 3.0e38f;
    const float4* c4 = (const float4*)cs;
    for (int k = lo >> 2; k < (hi >> 2); ++k) {
        const float4 c = c4[k];                  // independent: pipelined
        m0 = fminf(m0, fminf(fabsf(x - c.x), fabsf(x - c.y)));
        m1 = fminf(m1, fminf(fabsf(x - c.z), fabsf(x - c.w)));
    }
    float m = fminf(m0, m1);

    float bl = (lo == 0)    ? 3.0e38f
             : x - (LOF + (float)(bucket_of(cs[lo]) + 1) * BWF);
    float br = (hi >= NPTS) ? 3.0e38f
             : (LOF + (float)bucket_of(cs[hi - 1]) * BWF) - x;

    while (m > fminf(bl, br)) {                  // rare expansion
        if (bl <= br) {
            const int nlo = max(lo - KEXP, 0);
            for (int k = nlo >> 2; k < (lo >> 2); ++k) {
                const float4 c = c4[k];
                m = fminf(m, fminf(fminf(fabsf(x - c.x), fabsf(x - c.y)),
                                   fminf(fabsf(x - c.z), fabsf(x - c.w))));
            }
            lo = nlo;
            bl = (lo == 0) ? 3.0e38f
               : x - (LOF + (float)(bucket_of(cs[lo]) + 1) * BWF);
        } else {
            const int nhi = min(hi + KEXP, NPTS);
            for (int k = hi >> 2; k < (nhi >> 2); ++k) {
                const float4 c = c4[k];
                m = fminf(m, fminf(fminf(fabsf(x - c.x), fabsf(x - c.y)),
                                   fminf(fabsf(x - c.z), fabsf(x - c.w))));
            }
            hi = nhi;
            br = (hi >= NPTS) ? 3.0e38f
               : (LOF + (float)bucket_of(cs[hi - 1]) * BWF) - x;
        }
    }

    // block sum (128 thr = 2 waves), plain store
    float sum = m;
    #pragma unroll
    for (int off = 32; off > 0; off >>= 1)
        sum += __shfl_down(sum, off, 64);
    __shared__ float wsum[2];
    if ((t & 63) == 0) wsum[t >> 6] = sum;
    __syncthreads();
    if (t == 0) partials[blockIdx.x] = wsum[0] + wsum[1];
}

// K3: one block sums the 384 partials -> out = sum / NPTS.
__global__ __launch_bounds__(128) void final_kernel(
    const float* __restrict__ partials, float* __restrict__ out)
{
    const int t = threadIdx.x;
    float sum = partials[t] + partials[t + 128] + partials[t + 256];
    #pragma unroll
    for (int off = 32; off > 0; off >>= 1)
        sum += __shfl_down(sum, off, 64);
    __shared__ float wsum[2];
    if ((t & 63) == 0) wsum[t >> 6] = sum;
    __syncthreads();
    if (t == 0) out[0] = (wsum[0] + wsum[1]) * (1.0f / NPTS);
}

extern "C" void kernel_launch(void* const* d_in, const int* in_sizes, int n_in,
                              void* d_out, int out_size, void* d_ws, size_t ws_size,
                              hipStream_t stream) {
    const float* pred   = (const float*)d_in[0];
    const float* target = (const float*)d_in[1];
    float* out = (float*)d_out;
    float* wsf = (float*)d_ws;

    float* sorted   = wsf + WS_SORTED;
    int*   start    = (int*)(wsf + WS_START);
    float* qv       = wsf + WS_QV;
    float* partials = wsf + WS_PART;

    build_kernel<<<6, BTHREADS, 0, stream>>>(pred, target, sorted, start, qv);
    query_kernel<<<QBLKS, QTHREADS, 0, stream>>>(qv, sorted, start, partials);
    final_kernel<<<1, 128, 0, stream>>>(partials, out);
}

// Round 11
// 13.567 us; speedup vs baseline: 5.5508x; 1.4503x over previous
//
#include <hip/hip_runtime.h>

#define NPTS 8192
#define G 4096                      // buckets per plane
#define LOF (-6.0f)
#define BWF (12.0f / (float)G)      // bucket width
#define INVW ((float)G / 12.0f)
#define THREADS 1024
#define VPT (NPTS / THREADS)        // 8 candidates per thread
#define BPT (G / THREADS)           // 4 bins per thread (scan)
#define NBLK 48                     // 6 planes x 8 query-slices
#define KWIN 16                     // initial one-sided window (positions)
#define KEXP 32                     // expansion step (positions)

__device__ __forceinline__ int bucket_of(float v) {
    int b = (int)((v - LOF) * INVW);
    return min(max(b, 0), G - 1);
}

// One fused kernel: block = (plane p, query-slice s). The block counting-sorts
// plane p's 8192 values into LDS (hist -> shfl scan -> scatter), then its 1024
// threads each answer ONE query (the other array's values, same channel)
// entirely from LDS. No intermediate global data. Exact: position-window scan
// + bucket-edge stop bounds (valid for any intra-bucket scatter order).
__global__ __launch_bounds__(THREADS) void chamfer_fused_kernel(
    const float* __restrict__ pred, const float* __restrict__ target,
    float* __restrict__ partials)
{
    const int b = blockIdx.x;
    const int p = b >> 3, s = b & 7;      // plane 0..5, slice 0..7
    const int arr = p / 3, ch = p - arr * 3;
    const float* csrc = arr ? target : pred;   // candidates: this plane's array
    const float* qsrc = arr ? pred   : target; // queries: the other array

    __shared__ unsigned hist[G + 1];      // counts -> CSR starts (+sentinel)
    __shared__ unsigned curs[G];          // scatter cursors
    __shared__ __align__(16) float sv[NPTS];  // bucket-sorted values
    __shared__ unsigned wtot[THREADS / 64];
    __shared__ float    wsum[THREADS / 64];

    const int t = threadIdx.x, lane = t & 63, wave = t >> 6;

    // Issue the query load early (independent of the build phases).
    const float x = qsrc[(s * THREADS + t) * 3 + ch];

    float v[VPT];
    #pragma unroll
    for (int j = 0; j < VPT; ++j)
        v[j] = csrc[(t + j * THREADS) * 3 + ch];

    for (int i = t; i < G; i += THREADS) hist[i] = 0u;
    __syncthreads();

    #pragma unroll
    for (int j = 0; j < VPT; ++j)
        atomicAdd(&hist[bucket_of(v[j])], 1u);
    __syncthreads();

    // Exclusive scan over G bins (4 bins/thread, shfl within wave, LDS across)
    unsigned cnt[BPT], tsum = 0;
    #pragma unroll
    for (int j = 0; j < BPT; ++j) { cnt[j] = hist[t * BPT + j]; tsum += cnt[j]; }

    unsigned inc = tsum;
    #pragma unroll
    for (int off = 1; off < 64; off <<= 1) {
        unsigned n = __shfl_up(inc, off, 64);
        if (lane >= off) inc += n;
    }
    if (lane == 63) wtot[wave] = inc;
    __syncthreads();
    unsigned woff = 0;
    for (int w = 0; w < wave; ++w) woff += wtot[w];
    unsigned run = woff + (inc - tsum);

    #pragma unroll
    for (int j = 0; j < BPT; ++j) {       // own bins only: race-free
        hist[t * BPT + j] = run;          // counts -> exclusive starts
        curs[t * BPT + j] = run;
        run += cnt[j];
    }
    if (t == 0) hist[G] = NPTS;
    __syncthreads();

    #pragma unroll
    for (int j = 0; j < VPT; ++j) {
        const unsigned pos = atomicAdd(&curs[bucket_of(v[j])], 1u);
        sv[pos] = v[j];                   // intra-bucket order irrelevant (min)
    }
    __syncthreads();

    // ---- query from LDS ----
    const int bx = bucket_of(x);
    const int p0 = (int)hist[bx], p1 = (int)hist[bx + 1];

    int lo = max(p0 - KWIN, 0) & ~3;
    int hi = min(p1 + KWIN, NPTS);
    hi = (hi + 3) & ~3;

    const float4* c4 = (const float4*)sv;
    float m0 = 3.0e38f, m1 = 3.0e38f;
    for (int k = lo >> 2; k < (hi >> 2); ++k) {
        const float4 c = c4[k];
        m0 = fminf(m0, fminf(fabsf(x - c.x), fabsf(x - c.y)));
        m1 = fminf(m1, fminf(fabsf(x - c.z), fabsf(x - c.w)));
    }
    float m = fminf(m0, m1);

    // unscanned-lower values < upper edge of bucket(sv[lo]);
    // unscanned-higher values >= lower edge of bucket(sv[hi-1]).
    float bl = (lo == 0)    ? 3.0e38f
             : x - (LOF + (float)(bucket_of(sv[lo]) + 1) * BWF);
    float br = (hi >= NPTS) ? 3.0e38f
             : (LOF + (float)bucket_of(sv[hi - 1]) * BWF) - x;

    while (m > fminf(bl, br)) {           // rare; LDS-cheap
        if (bl <= br) {
            const int nlo = max(lo - KEXP, 0);
            for (int k = nlo >> 2; k < (lo >> 2); ++k) {
                const float4 c = c4[k];
                m = fminf(m, fminf(fminf(fabsf(x - c.x), fabsf(x - c.y)),
                                   fminf(fabsf(x - c.z), fabsf(x - c.w))));
            }
            lo = nlo;
            bl = (lo == 0) ? 3.0e38f
               : x - (LOF + (float)(bucket_of(sv[lo]) + 1) * BWF);
        } else {
            const int nhi = min(hi + KEXP, NPTS);
            for (int k = hi >> 2; k < (nhi >> 2); ++k) {
                const float4 c = c4[k];
                m = fminf(m, fminf(fminf(fabsf(x - c.x), fabsf(x - c.y)),
                                   fminf(fabsf(x - c.z), fabsf(x - c.w))));
            }
            hi = nhi;
            br = (hi >= NPTS) ? 3.0e38f
               : (LOF + (float)bucket_of(sv[hi - 1]) * BWF) - x;
        }
    }

    // block sum (fixed order -> deterministic), plain store
    float sum = m;
    #pragma unroll
    for (int off = 32; off > 0; off >>= 1)
        sum += __shfl_down(sum, off, 64);
    if (lane == 0) wsum[wave] = sum;
    __syncthreads();
    if (t == 0) {
        float tot = 0.f;
        #pragma unroll
        for (int w = 0; w < THREADS / 64; ++w) tot += wsum[w];
        partials[b] = tot;
    }
}

// Final: one wave sums the 48 block-partials -> out = sum / NPTS.
__global__ __launch_bounds__(64) void final_kernel(
    const float* __restrict__ partials, float* __restrict__ out)
{
    const int t = threadIdx.x;
    float s = (t < NBLK) ? partials[t] : 0.f;
    #pragma unroll
    for (int off = 32; off > 0; off >>= 1)
        s += __shfl_down(s, off, 64);
    if (t == 0) out[0] = s * (1.0f / NPTS);
}

extern "C" void kernel_launch(void* const* d_in, const int* in_sizes, int n_in,
                              void* d_out, int out_size, void* d_ws, size_t ws_size,
                              hipStream_t stream) {
    const float* pred   = (const float*)d_in[0];
    const float* target = (const float*)d_in[1];
    float* out = (float*)d_out;
    float* partials = (float*)d_ws;   // [NBLK]

    chamfer_fused_kernel<<<NBLK, THREADS, 0, stream>>>(pred, target, partials);
    final_kernel<<<1, 64, 0, stream>>>(partials, out);
}